// Round 6
// baseline (321.993 us; speedup 1.0000x reference)
//
#include <hip/hip_runtime.h>
#include <math.h>

#define BATCH 2048
#define LDIM 64
#define EDIM 256
#define UDIM 512
#define G 8
#define HLP 516  // padded hidden-row stride (floats): breaks 8-way bank aliasing

typedef __attribute__((ext_vector_type(8))) _Float16 half8;
typedef __attribute__((ext_vector_type(4))) float floatx4;

__device__ inline float tanh_fast(float x) {
    float t = __builtin_amdgcn_exp2f(x * 2.88539008177792681f);
    return 1.f - 2.f * __builtin_amdgcn_rcpf(t + 1.f);
}
__device__ inline half8 cvt8(float4 f0, float4 f1) {
    half8 h;
    h[0] = (_Float16)f0.x; h[1] = (_Float16)f0.y;
    h[2] = (_Float16)f0.z; h[3] = (_Float16)f0.w;
    h[4] = (_Float16)f1.x; h[5] = (_Float16)f1.y;
    h[6] = (_Float16)f1.z; h[7] = (_Float16)f1.w;
    return h;
}
// B-fragment pointer: layout [kc][ntg(32)][lane(64)][8 fp16]
__device__ inline const half8* bfrag(const unsigned short* F, int kc, int ntg, int l) {
    return (const half8*)(F + ((((size_t)kc * 32 + ntg) * 64 + l) << 3));
}

// ---- prep: W[K][512] fp32 -> fp16 B-fragments via coalesced LDS slab. ----
__global__ __launch_bounds__(256) void prep_frag(const float* __restrict__ W1,
                                                 const float* __restrict__ W2,
                                                 unsigned short* __restrict__ F1,
                                                 unsigned short* __restrict__ F2) {
    __shared__ float S[32 * 128];
    int bid = blockIdx.x;
    const float* W; unsigned short* F; int kc, grp;
    if (bid < 32) { W = W1; F = F1; kc = bid >> 2; grp = bid & 3; }
    else { bid -= 32; W = W2; F = F2; kc = bid >> 2; grp = bid & 3; }
    const int tid = threadIdx.x;
    const float* src = W + (size_t)kc * 32 * UDIM + grp * 128;
    float4* Sv = (float4*)S;
#pragma unroll
    for (int i = 0; i < 4; ++i) {
        int f = tid + i * 256;
        int k = f >> 5, c4 = f & 31;
        Sv[f] = *(const float4*)(src + (size_t)k * UDIM + c4 * 4);
    }
    __syncthreads();
#pragma unroll
    for (int i = 0; i < 2; ++i) {
        int u = tid + i * 256;
        int lane = u & 63, ntl = u >> 6;
        int n_loc = ntl * 16 + (lane & 15);
        int k0 = (lane >> 4) * 8;
        half8 h;
#pragma unroll
        for (int j = 0; j < 8; ++j)
            h[j] = (_Float16)S[(k0 + j) * 128 + n_loc];
        int ntg = grp * 8 + ntl;
        *(half8*)(F + (((size_t)kc * 32 + ntg) * 64 + lane) * 8) = h;
    }
}

// ---- main: persistent block = G batches. 1024 thr / 16 waves, wave owns 32 cols.
// A double-buffered in LDS; next batch's HBM loads in flight across whole iteration.
__global__ __launch_bounds__(1024, 4) void attn_main(
    const float* __restrict__ feat, const unsigned short* __restrict__ F1,
    const unsigned short* __restrict__ F2, const float* __restrict__ hidden,
    const float* __restrict__ b1, const float* __restrict__ b2,
    const float* __restrict__ Vw, const float* __restrict__ bv,
    float* __restrict__ ctx_out, float* __restrict__ w_out)
{
    __shared__ _Float16 lA[2][16384];   // 32 KB each: [kc(8)][mt(4)][lane^kc][8]
    __shared__ float hl[8 * HLP];       // 16.1 KB padded hidden rows
    __shared__ float ph_all[G][UDIM];   // 16 KB
    __shared__ float Vl[UDIM];
    __shared__ float scp[16][64];
    __shared__ float wsm[64];
    __shared__ float ctxp[4][256];

    const int tid = threadIdx.x;
    const int w = tid >> 6;
    const int l = tid & 63;
    const size_t b0 = (size_t)blockIdx.x * G;

    // staging geometry: thread -> (row 0..63, 16-col seg 0..15)
    const int ar = tid >> 4, ac = (tid & 15) * 16;
    const int skc = (tid & 15) >> 1, so = (tid & 1) * 2;
    const int smt = ar >> 4, srr = ar & 15;

    // ---- issue g=0 feature loads FIRST (fly during ph compute) ----
    const float4* gp0 = (const float4*)(feat + b0 * (LDIM * EDIM) + ar * EDIM + ac);
    float4 s0 = gp0[0], s1 = gp0[1], s2 = gp0[2], s3 = gp0[3];

    // stage hidden rows (8 x 512, padded) + V
    {
        int f = tid * 4, row = f >> 9, col = f & 511;
        *(float4*)&hl[row * HLP + col] =
            *(const float4*)(hidden + b0 * UDIM + f);
    }
    if (tid < 512) Vl[tid] = Vw[tid];
    __syncthreads();

    // ---- ph = hidden @ W2 + b1 + b2 via MFMA (rows 8..15 duplicate, ignored) ----
    {
        floatx4 pacc[2];
        pacc[0] = (floatx4){0.f, 0.f, 0.f, 0.f};
        pacc[1] = (floatx4){0.f, 0.f, 0.f, 0.f};
        const float* hrow = hl + (l & 7) * HLP + ((l >> 4) << 3);
#pragma unroll 2
        for (int kc = 0; kc < 16; ++kc) {
            float4 h0 = *(const float4*)(hrow + kc * 32);
            float4 h1 = *(const float4*)(hrow + kc * 32 + 4);
            half8 a = cvt8(h0, h1);
#pragma unroll
            for (int nt = 0; nt < 2; ++nt) {
                half8 bf = *bfrag(F2, kc, w * 2 + nt, l);
                pacc[nt] = __builtin_amdgcn_mfma_f32_16x16x32_f16(a, bf, pacc[nt], 0, 0, 0);
            }
        }
#pragma unroll
        for (int nt = 0; nt < 2; ++nt) {
            const int n = (w * 2 + nt) * 16 + (l & 15);
            const float bias = b1[n] + b2[n];
            if ((l >> 4) < 2) {
#pragma unroll
                for (int r = 0; r < 4; ++r)
                    ph_all[(l >> 4) * 4 + r][n] = pacc[nt][r] + bias;
            }
        }
    }
    // write A(g=0) into buffer 0
    {
        _Float16* dst = &lA[0][((skc * 4 + smt) * 64) * 8];
        *(half8*)(dst + (((so * 16 + srr) ^ skc)) * 8)       = cvt8(s0, s1);
        *(half8*)(dst + ((((so + 1) * 16 + srr) ^ skc)) * 8) = cvt8(s2, s3);
    }
    __syncthreads();

    const float bvv = bv[0];

    for (int g = 0; g < G; ++g) {
        const int cur = g & 1;
        const size_t b = b0 + g;
        const float* fb = feat + b * (LDIM * EDIM);

        // ---- prefetch next batch (in flight across the whole iteration) ----
        float4 p0, p1, p2, p3;
        if (g < G - 1) {
            const float4* gp = (const float4*)(fb + LDIM * EDIM + ar * EDIM + ac);
            p0 = gp[0]; p1 = gp[1]; p2 = gp[2]; p3 = gp[3];
        }

        // ---- GEMM: 8 kc, wave owns cols [(w*2)*16, +32) ----
        floatx4 acc[2][4];
#pragma unroll
        for (int i = 0; i < 2; ++i)
#pragma unroll
            for (int j = 0; j < 4; ++j) acc[i][j] = (floatx4){0.f, 0.f, 0.f, 0.f};
#pragma unroll
        for (int kc = 0; kc < 8; ++kc) {
            half8 B0 = *bfrag(F1, kc, w * 2 + 0, l);
            half8 B1 = *bfrag(F1, kc, w * 2 + 1, l);
            half8 a[4];
#pragma unroll
            for (int mt = 0; mt < 4; ++mt)
                a[mt] = *(const half8*)&lA[cur][((kc * 4 + mt) * 64 + (l ^ kc)) * 8];
#pragma unroll
            for (int mt = 0; mt < 4; ++mt) {
                acc[0][mt] = __builtin_amdgcn_mfma_f32_16x16x32_f16(a[mt], B0, acc[0][mt], 0, 0, 0);
                acc[1][mt] = __builtin_amdgcn_mfma_f32_16x16x32_f16(a[mt], B1, acc[1][mt], 0, 0, 0);
            }
        }

        // ---- epilogue: tanh(acc + ph) * V -> per-row score partials ----
        float sv[4][4];
#pragma unroll
        for (int mt = 0; mt < 4; ++mt)
#pragma unroll
            for (int r = 0; r < 4; ++r) sv[mt][r] = 0.f;
#pragma unroll
        for (int nt = 0; nt < 2; ++nt) {
            const int n = (w * 2 + nt) * 16 + (l & 15);
            const float phn = ph_all[g][n];
            const float vn  = Vl[n];
#pragma unroll
            for (int mt = 0; mt < 4; ++mt)
#pragma unroll
                for (int r = 0; r < 4; ++r)
                    sv[mt][r] += tanh_fast(acc[nt][mt][r] + phn) * vn;
        }
#pragma unroll
        for (int mt = 0; mt < 4; ++mt)
#pragma unroll
            for (int r = 0; r < 4; ++r) {
                float v = sv[mt][r];
                v += __shfl_xor(v, 1);
                v += __shfl_xor(v, 2);
                v += __shfl_xor(v, 4);
                v += __shfl_xor(v, 8);
                if ((l & 15) == 0) scp[w][mt * 16 + (l >> 4) * 4 + r] = v;
            }
        __syncthreads();

        // ---- softmax over L=64 ----
        if (tid < 64) {
            float s = bvv;
#pragma unroll
            for (int wv = 0; wv < 16; ++wv) s += scp[wv][tid];
            float m = s;
            m = fmaxf(m, __shfl_xor(m, 32));
            m = fmaxf(m, __shfl_xor(m, 16));
            m = fmaxf(m, __shfl_xor(m, 8));
            m = fmaxf(m, __shfl_xor(m, 4));
            m = fmaxf(m, __shfl_xor(m, 2));
            m = fmaxf(m, __shfl_xor(m, 1));
            float e = __builtin_amdgcn_exp2f((s - m) * 1.44269504088896341f);
            float sum = e;
            sum += __shfl_xor(sum, 32);
            sum += __shfl_xor(sum, 16);
            sum += __shfl_xor(sum, 8);
            sum += __shfl_xor(sum, 4);
            sum += __shfl_xor(sum, 2);
            sum += __shfl_xor(sum, 1);
            float wgt = e / sum;
            wsm[tid] = wgt;
            w_out[b * LDIM + tid] = wgt;
        }
        __syncthreads();

        // ---- ctx partials: quarter h sums 16 rows, fp32 from global (L1/L2-hot) ----
        {
            const int h = tid >> 8, e = tid & 255;
            const float* fr = fb + (h * 16) * EDIM + e;
            float c = 0.f;
#pragma unroll
            for (int i = 0; i < 16; ++i)
                c = fmaf(wsm[h * 16 + i], fr[i * EDIM], c);
            ctxp[h][e] = c;
        }
        // ---- write A(g+1) into other buffer ----
        if (g < G - 1) {
            _Float16* dst = &lA[cur ^ 1][((skc * 4 + smt) * 64) * 8];
            *(half8*)(dst + (((so * 16 + srr) ^ skc)) * 8)       = cvt8(p0, p1);
            *(half8*)(dst + ((((so + 1) * 16 + srr) ^ skc)) * 8) = cvt8(p2, p3);
        }
        __syncthreads();

        if (tid < 256)
            ctx_out[b * EDIM + tid] =
                ctxp[0][tid] + ctxp[1][tid] + ctxp[2][tid] + ctxp[3][tid];
    }
}

extern "C" void kernel_launch(void* const* d_in, const int* in_sizes, int n_in,
                              void* d_out, int out_size, void* d_ws, size_t ws_size,
                              hipStream_t stream) {
    const float* features = (const float*)d_in[0];
    const float* hidden   = (const float*)d_in[1];
    const float* W1       = (const float*)d_in[2];
    const float* b1       = (const float*)d_in[3];
    const float* W2       = (const float*)d_in[4];
    const float* b2       = (const float*)d_in[5];
    const float* Vw       = (const float*)d_in[6];
    const float* bv       = (const float*)d_in[7];

    float* ctx_out = (float*)d_out;
    float* w_out   = (float*)d_out + (size_t)BATCH * EDIM;

    unsigned short* F1 = (unsigned short*)d_ws;            // 256 KB
    unsigned short* F2 = F1 + (size_t)8 * 32 * 64 * 8;     // 512 KB

    prep_frag<<<dim3(96), dim3(256), 0, stream>>>(W1, W2, F1, F2);
    attn_main<<<dim3(BATCH / G), dim3(1024), 0, stream>>>(
        features, F1, F2, hidden, b1, b2, Vw, bv, ctx_out, w_out);
}